// Round 9
// baseline (248.133 us; speedup 1.0000x reference)
//
#include <hip/hip_runtime.h>

#define N_NODES 16384
#define N_EDGES 262144
#define EP (N_EDGES + N_NODES)   // with self-loops
#define HID 128
#define ENC 768
#define EPSV 1e-5f

typedef unsigned short u16;
typedef unsigned char u8;
using f32x4  = __attribute__((ext_vector_type(4))) float;
using bf16x8 = __attribute__((ext_vector_type(8))) short;
using v2f    = __attribute__((ext_vector_type(2))) float;

__device__ __forceinline__ float wave_sum(float v){
  #pragma unroll
  for(int m=32;m>=1;m>>=1) v += __shfl_xor(v, m, 64);
  return v;
}
__device__ __forceinline__ unsigned bf16rtne(float f){
  const unsigned u = __float_as_uint(f);
  return (u + 0x7fffu + ((u>>16)&1u)) >> 16;
}
__device__ __forceinline__ unsigned pack2(float a, float b){
  return bf16rtne(a) | (bf16rtne(b) << 16);
}
__device__ __forceinline__ float bf2f(u16 h){ return __uint_as_float(((unsigned)h) << 16); }
__device__ __forceinline__ float plo(unsigned u){ return __uint_as_float(u << 16); }
__device__ __forceinline__ float phi(unsigned u){ return __uint_as_float(u & 0xffff0000u); }
__device__ __forceinline__ u8 f2fp8(float v){
  return (u8)(__builtin_amdgcn_cvt_pk_fp8_f32(v, v, 0, false) & 0xff);
}

// 2 bf16 channels (one dword from each table)
#define CH2(ad, bd, sx, sy, q) { \
  q = fmaf(sx, __builtin_fabsf(plo(ad)+plo(bd)), q); \
  q = fmaf(sy, __builtin_fabsf(phi(ad)+phi(bd)), q); }

// 4 channels: fp8 dword (src table) + 2 bf16 dwords (dst table)
#define DWX(ax, blo, bhi, s4, q) { \
  const v2f A01 = __builtin_amdgcn_cvt_pk_f32_fp8(ax, false); \
  const v2f A23 = __builtin_amdgcn_cvt_pk_f32_fp8(ax, true);  \
  q = fmaf(s4.x, __builtin_fabsf(A01.x+plo(blo)), q); \
  q = fmaf(s4.y, __builtin_fabsf(A01.y+phi(blo)), q); \
  q = fmaf(s4.z, __builtin_fabsf(A23.x+plo(bhi)), q); \
  q = fmaf(s4.w, __builtin_fabsf(A23.y+phi(bhi)), q); }

// ---- merged prep: lin1->bf16 score tables (+dots,+xpad), Wtb, histogram, W2@att2 ----
#define LIN1_BLKS (N_NODES/4)            // 4096 (one wave per node)
#define WPREP_BLKS (2*ENC*HID/256)       // 768
#define HIST_BLKS (EP/256)               // 1088
#define W2A_BLKS 258
__global__ __launch_bounds__(256) void prep_kernel(
    const float* __restrict__ x,
    const float* __restrict__ W1l, const float* __restrict__ b1l,
    const float* __restrict__ W1r, const float* __restrict__ b1r,
    const float* __restrict__ att1,
    const float* __restrict__ W2l, const float* __restrict__ W2r,
    const float* __restrict__ b2l, const float* __restrict__ b2r,
    const float* __restrict__ att2,
    const int* __restrict__ ei,
    u16* __restrict__ xl1b, u16* __restrict__ xr1b,
    float4* __restrict__ xpad,
    float* __restrict__ dotl1, float* __restrict__ dotr1,
    u16* __restrict__ Wtb, float* __restrict__ w2a,
    int* __restrict__ hist){
  const int bid = blockIdx.x;
  if(bid < LIN1_BLKS){
    const int lane = threadIdx.x & 63;
    const int n = bid*4 + (threadIdx.x >> 6);
    const float x0 = x[n*3], x1 = x[n*3+1], x2 = x[n*3+2];
    const int c0 = lane, c1 = lane + 64;
    const float la = x0*W1l[c0] + x1*W1l[HID+c0] + x2*W1l[2*HID+c0] + b1l[c0];
    const float lb = x0*W1l[c1] + x1*W1l[HID+c1] + x2*W1l[2*HID+c1] + b1l[c1];
    const float ra = x0*W1r[c0] + x1*W1r[HID+c0] + x2*W1r[2*HID+c0] + b1r[c0];
    const float rb = x0*W1r[c1] + x1*W1r[HID+c1] + x2*W1r[2*HID+c1] + b1r[c1];
    const float aa = att1[c0], ab = att1[c1];
    const float dl = wave_sum(la*aa + lb*ab);
    const float dr = wave_sum(ra*aa + rb*ab);
    if(lane == 0){
      dotl1[n] = 0.6f*dl; dotr1[n] = 0.6f*dr;
      xpad[n] = make_float4(x0, x1, x2, 0.f);
    }
    xl1b[n*HID+c0] = (u16)bf16rtne(la); xl1b[n*HID+c1] = (u16)bf16rtne(lb);
    xr1b[n*HID+c0] = (u16)bf16rtne(ra); xr1b[n*HID+c1] = (u16)bf16rtne(rb);
  } else if(bid < LIN1_BLKS + WPREP_BLKS){
    const int idx = (bid - LIN1_BLKS)*256 + threadIdx.x;
    const int n = idx >> 7, k = idx & 127;
    const float v = (n < ENC) ? W2l[k*ENC + n] : W2r[k*ENC + (n-ENC)];
    Wtb[idx] = (u16)bf16rtne(v);
  } else if(bid < LIN1_BLKS + WPREP_BLKS + HIST_BLKS){
    const int i = (bid - LIN1_BLKS - WPREP_BLKS)*256 + threadIdx.x;
    const int dst = (i < N_EDGES) ? ei[N_EDGES + i] : (i - N_EDGES);
    atomicAdd(&hist[dst], 1);
  } else {
    const int idx = bid - (LIN1_BLKS + WPREP_BLKS + HIST_BLKS);
    const float* src = (idx < 128) ? (W2l + (size_t)idx*ENC)
                     : (idx < 256) ? (W2r + (size_t)(idx-128)*ENC)
                     : (idx == 256) ? b2l : b2r;
    float partial = 0.f;
    for(int c = threadIdx.x; c < ENC; c += 256) partial += src[c]*att2[c];
    partial = wave_sum(partial);
    __shared__ float red4[4];
    if((threadIdx.x & 63) == 0) red4[threadIdx.x >> 6] = partial;
    __syncthreads();
    if(threadIdx.x == 0) w2a[idx] = red4[0]+red4[1]+red4[2]+red4[3];
  }
}

// ---- single-block exclusive scan over N=16384 (1024 thr x 16 items) ----
__global__ __launch_bounds__(1024) void scan_kernel(
    const int* __restrict__ hist, int* __restrict__ rowstart){
  __shared__ int sums[1024];
  const int t = threadIdx.x;
  const int base = t*16;
  int loc[16];
  int s = 0;
  #pragma unroll
  for(int i=0;i<16;i++){ loc[i] = s; s += hist[base+i]; }
  sums[t] = s;
  __syncthreads();
  for(int off=1; off<1024; off<<=1){
    int v = 0;
    if(t >= off) v = sums[t-off];
    __syncthreads();
    if(t >= off) sums[t] += v;
    __syncthreads();
  }
  const int prev = (t==0) ? 0 : sums[t-1];
  #pragma unroll
  for(int i=0;i<16;i++) rowstart[base+i] = prev + loc[i];
  if(t == 1023) rowstart[N_NODES] = EP;
}

// ---- CSR build: scatter packed (src | dst<<14) into dst-sorted order ----
__global__ __launch_bounds__(256) void scatter_kernel(
    const int* __restrict__ ei, const int* __restrict__ rowstart,
    int* __restrict__ cursor, unsigned* __restrict__ sedge){
  const int i = blockIdx.x*256 + threadIdx.x;        // exactly EP threads
  const int src = (i < N_EDGES) ? ei[i]           : (i - N_EDGES);
  const int dst = (i < N_EDGES) ? ei[N_EDGES + i] : (i - N_EDGES);
  const int pos = rowstart[dst] + atomicAdd(&cursor[dst], 1);
  sedge[pos] = (unsigned)src | ((unsigned)dst << 14);
}

// ---- layer-1 scores, edge-parallel (lane = edge), bf16 tables ----
__global__ __launch_bounds__(256) void score1_kernel(
    const u16* __restrict__ xl1b, const u16* __restrict__ xr1b,
    const float* __restrict__ att1,
    const float* __restrict__ dotl1, const float* __restrict__ dotr1,
    const unsigned* __restrict__ sedge, float* __restrict__ w1){
  __shared__ __align__(16) float sg[HID];
  const int t = threadIdx.x;
  if(t < HID) sg[t] = 0.4f*att1[t];
  __syncthreads();
  const int p = blockIdx.x*256 + t;
  const unsigned v = sedge[p];
  const int s = v & 16383, d = v >> 14;
  const uint4* A = (const uint4*)(xl1b + (size_t)s*HID);
  const uint4* B = (const uint4*)(xr1b + (size_t)d*HID);
  const float4* S4 = (const float4*)sg;
  float q0=0.f,q1=0.f,q2=0.f,q3=0.f;
  #pragma unroll
  for(int k=0;k<16;k++){                     // 16 uint4 x 8 bf16 channels = 128
    const uint4 a = A[k], b = B[k];
    const float4 s0 = S4[2*k], s1 = S4[2*k+1];
    CH2(a.x,b.x,s0.x,s0.y,q0) CH2(a.y,b.y,s0.z,s0.w,q1)
    CH2(a.z,b.z,s1.x,s1.y,q2) CH2(a.w,b.w,s1.z,s1.w,q3)
  }
  w1[p] = __expf(q0+q1+q2+q3 + dotl1[s] + dotr1[d]);
}

// ---- layer-1 aggregate: 3-dim (commuted through W1l), lane = node ----
__global__ __launch_bounds__(256) void agg1_kernel(
    const unsigned* __restrict__ sedge, const float* __restrict__ w1,
    const float4* __restrict__ xpad, const int* __restrict__ rowstart,
    float4* __restrict__ agg4){
  const int n = blockIdx.x*256 + threadIdx.x;        // 64 blocks
  const int p1 = rowstart[n+1];
  float a0=0.f,a1=0.f,a2=0.f,dn=0.f;
  for(int p=rowstart[n]; p<p1; ++p){
    const unsigned v = sedge[p];
    const float w = w1[p];
    const float4 xv = xpad[v & 16383];
    a0 += w*xv.x; a1 += w*xv.y; a2 += w*xv.z; dn += w;
  }
  agg4[n] = make_float4(a0,a1,a2,dn);
}

// ---- h1 = ELU(LN(agg3/denom @ W1l + b1l + bias1)); emits h1b/h1p + layer-2 dots ----
__global__ __launch_bounds__(256) void h1lin_kernel(
    const float4* __restrict__ agg4,
    const float* __restrict__ W1l, const float* __restrict__ b1l,
    const float* __restrict__ bias1,
    const float* __restrict__ g1, const float* __restrict__ b1,
    const float* __restrict__ w2a,
    u16* __restrict__ h1b, unsigned* __restrict__ h1p,
    float* __restrict__ dotl2, float* __restrict__ dotr2){
  const int lane = threadIdx.x & 63;
  const int n = blockIdx.x*4 + (threadIdx.x >> 6);
  const float4 ag = agg4[n];
  const float inv = 1.f/ag.w;
  const float a0 = ag.x*inv, a1 = ag.y*inv, a2 = ag.z*inv;
  const int c0 = lane, c1 = lane + 64;
  const float y0 = a0*W1l[c0] + a1*W1l[HID+c0] + a2*W1l[2*HID+c0] + b1l[c0] + bias1[c0];
  const float y1 = a0*W1l[c1] + a1*W1l[HID+c1] + a2*W1l[2*HID+c1] + b1l[c1] + bias1[c1];
  const float mu  = wave_sum(y0+y1) * (1.f/HID);
  const float d0 = y0-mu, d1 = y1-mu;
  const float var = wave_sum(d0*d0 + d1*d1) * (1.f/HID);
  const float r = rsqrtf(var + EPSV);
  float z0 = d0*r*g1[c0] + b1[c0];
  float z1 = d1*r*g1[c1] + b1[c1];
  z0 = z0 > 0.f ? z0 : expm1f(z0);        // ELU(alpha=1)
  z1 = z1 > 0.f ? z1 : expm1f(z1);
  h1b[n*HID+c0] = (u16)bf16rtne(z0);
  h1b[n*HID+c1] = (u16)bf16rtne(z1);
  h1p[n*64+lane] = pack2(z0, z1);
  float dl2 = z0*w2a[lane]     + z1*w2a[lane+64];
  float dr2 = z0*w2a[128+lane] + z1*w2a[128+lane+64];
  #pragma unroll
  for(int m=32;m>=1;m>>=1){
    dl2 += __shfl_xor(dl2, m, 64);
    dr2 += __shfl_xor(dr2, m, 64);
  }
  if(lane == 0){
    dotl2[n] = 0.6f*(dl2 + w2a[256]);
    dotr2[n] = 0.6f*(dr2 + w2a[257]);
  }
}

// ---- MFMA GEMM: l-half -> fp8 xl8 (random src gather), r-half -> bf16 xr2u ----
#define LBM 128
#define LBN 128
__global__ __launch_bounds__(256) void mfma_lin2_kernel(
    const u16* __restrict__ h1b, const u16* __restrict__ Wtb,
    const float* __restrict__ b2l, const float* __restrict__ b2r,
    u8* __restrict__ xl8, u16* __restrict__ xr2u){
  __shared__ __align__(16) u16 Cs[LBM*128];   // 32 KB bounce, swizzled rows
  const int t = threadIdx.x;
  const int mb = blockIdx.x * LBM;
  const int nb = blockIdx.y * LBN;
  const int w = t >> 6, lane = t & 63;
  const int l15 = lane & 15, g = lane >> 4;
  const int ar0 = mb + w*32 + l15, ar1 = ar0 + 16;
  bf16x8 a0[4], a1[4];
  #pragma unroll
  for(int ks=0;ks<4;ks++){
    a0[ks] = *(const bf16x8*)(h1b + (size_t)ar0*128 + ks*32 + g*8);
    a1[ks] = *(const bf16x8*)(h1b + (size_t)ar1*128 + ks*32 + g*8);
  }
  f32x4 acc0[8], acc1[8];
  #pragma unroll
  for(int j=0;j<8;j++){ acc0[j]=(f32x4){0,0,0,0}; acc1[j]=(f32x4){0,0,0,0}; }
  #pragma unroll
  for(int j=0;j<8;j++){
    const int brn = nb + j*16 + l15;
    #pragma unroll
    for(int ks=0;ks<4;ks++){
      const bf16x8 b = *(const bf16x8*)(Wtb + (size_t)brn*128 + ks*32 + g*8);
      acc0[j] = __builtin_amdgcn_mfma_f32_16x16x32_bf16(a0[ks], b, acc0[j], 0,0,0);
      acc1[j] = __builtin_amdgcn_mfma_f32_16x16x32_bf16(a1[ks], b, acc1[j], 0,0,0);
    }
  }
  if(nb < ENC){
    // fp8 epilogue (src score table)
    u8* Cs8 = (u8*)Cs;
    float biasj[8];
    #pragma unroll
    for(int j=0;j<8;j++) biasj[j] = b2l[nb + j*16 + l15];
    #pragma unroll
    for(int j=0;j<8;j++){
      const int col = j*16 + l15;
      #pragma unroll
      for(int r4=0;r4<4;r4++){
        const int row0 = w*32 + g*4 + r4;         // C/D: col=lane&15, row=(lane>>4)*4+reg
        Cs8[row0*128 + (col ^ ((row0&7)<<4))] = f2fp8(acc0[j][r4] + biasj[j]);
        const int row1 = row0 + 16;
        Cs8[row1*128 + (col ^ ((row1&7)<<4))] = f2fp8(acc1[j][r4] + biasj[j]);
      }
    }
    __syncthreads();
    #pragma unroll
    for(int idx=t; idx<LBM*8; idx+=256){
      const int row = idx >> 3, ch = idx & 7;
      const uint4 v = *(const uint4*)(Cs8 + row*128 + ((ch*16) ^ ((row&7)<<4)));
      *(uint4*)(xl8 + (size_t)(mb+row)*ENC + nb + ch*16) = v;
    }
  } else {
    // bf16 epilogue (dst score table — L1-local in edge-parallel reads)
    const float* bsrc = b2r + (nb - ENC);
    float biasj[8];
    #pragma unroll
    for(int j=0;j<8;j++) biasj[j] = bsrc[j*16 + l15];
    #pragma unroll
    for(int j=0;j<8;j++){
      const int coll = j*16 + l15;
      #pragma unroll
      for(int r4=0;r4<4;r4++){
        const int row0 = w*32 + g*4 + r4;
        *(u16*)((char*)Cs + row0*256 + ((coll*2) ^ ((row0&7)<<4))) =
            (u16)bf16rtne(acc0[j][r4] + biasj[j]);
        const int row1 = row0 + 16;
        *(u16*)((char*)Cs + row1*256 + ((coll*2) ^ ((row1&7)<<4))) =
            (u16)bf16rtne(acc1[j][r4] + biasj[j]);
      }
    }
    __syncthreads();
    u16* dst0 = xr2u + (nb - ENC);
    const int rr = t >> 4, cc = t & 15;
    #pragma unroll
    for(int it=0; it<8; ++it){
      const int row = it*16 + rr;
      const uint4 v = *(const uint4*)((const char*)Cs + row*256 + ((cc*16) ^ ((row&7)<<4)));
      *(uint4*)(dst0 + (size_t)(mb+row)*ENC + cc*8) = v;
    }
  }
}

// ---- layer-2 scores, edge-parallel: fp8 src row + bf16 dst row ----
__global__ __launch_bounds__(256) void score2_kernel(
    const u8* __restrict__ xl8, const u16* __restrict__ xr2u,
    const float* __restrict__ att2,
    const float* __restrict__ dotl2, const float* __restrict__ dotr2,
    const unsigned* __restrict__ sedge, float* __restrict__ w2){
  __shared__ __align__(16) float sg[ENC];
  const int t = threadIdx.x;
  for(int c=t; c<ENC; c+=256) sg[c] = 0.4f*att2[c];
  __syncthreads();
  const int p = blockIdx.x*256 + t;
  const unsigned v = sedge[p];
  const int s = v & 16383, d = v >> 14;
  const uint4* A = (const uint4*)(xl8 + (size_t)s*ENC);
  const uint4* B = (const uint4*)(xr2u + (size_t)d*ENC);
  const float4* S4 = (const float4*)sg;
  float q0=0.f,q1=0.f,q2=0.f,q3=0.f;
  #pragma unroll 4
  for(int k=0;k<48;k++){                 // 48 x 16 channels = 768  (R8 bug: was 12)
    const uint4 a = A[k];
    const uint4 b0 = B[2*k], b1 = B[2*k+1];
    const float4 s0 = S4[4*k], s1 = S4[4*k+1], s2 = S4[4*k+2], s3 = S4[4*k+3];
    DWX(a.x, b0.x, b0.y, s0, q0)
    DWX(a.y, b0.z, b0.w, s1, q1)
    DWX(a.z, b1.x, b1.y, s2, q2)
    DWX(a.w, b1.z, b1.w, s3, q3)
  }
  w2[p] = __expf(q0+q1+q2+q3 + dotl2[s] + dotr2[d]);
}

// ---- layer-2 aggregate: wave = node, no shuffles; gathers packed h1 ----
__global__ __launch_bounds__(256) void agg2_kernel(
    const unsigned* __restrict__ sedge, const float* __restrict__ w2,
    const unsigned* __restrict__ h1p, const int* __restrict__ rowstart,
    u16* __restrict__ aggb){
  const int lane = threadIdx.x & 63;
  const int n = blockIdx.x*4 + (threadIdx.x >> 6);
  float denom=0.f, acc0=0.f, acc1=0.f;
  int p = rowstart[n];
  const int p1 = rowstart[n+1];
  for(; p+3 < p1; p += 4){
    const unsigned v0 = sedge[p],   v1 = sedge[p+1];
    const unsigned v2 = sedge[p+2], v3 = sedge[p+3];
    const float w0 = w2[p], w1v = w2[p+1], w2v = w2[p+2], w3 = w2[p+3];
    const unsigned h0 = h1p[(v0 & 16383)*64 + lane];
    const unsigned h1 = h1p[(v1 & 16383)*64 + lane];
    const unsigned h2 = h1p[(v2 & 16383)*64 + lane];
    const unsigned h3 = h1p[(v3 & 16383)*64 + lane];
    denom += (w0+w1v) + (w2v+w3);
    acc0 += w0*plo(h0) + w1v*plo(h1) + w2v*plo(h2) + w3*plo(h3);
    acc1 += w0*phi(h0) + w1v*phi(h1) + w2v*phi(h2) + w3*phi(h3);
  }
  for(; p < p1; ++p){
    const unsigned v = sedge[p];
    const float w = w2[p];
    const unsigned h = h1p[(v & 16383)*64 + lane];
    denom += w; acc0 += w*plo(h); acc1 += w*phi(h);
  }
  const float inv = 1.f/denom;
  aggb[n*HID+lane]    = (u16)bf16rtne(acc0*inv);
  aggb[n*HID+lane+64] = (u16)bf16rtne(acc1*inv);
}

// ---- final fused: out = LN( aggb@W2l + b2l + bias2 + x@Wfc + bfc ) ----
#define YSTR 770
__global__ __launch_bounds__(256) void gemm3_mfma_kernel(
    const u16* __restrict__ aggb, const u16* __restrict__ Wtb,
    const float* __restrict__ b2l, const float* __restrict__ bias2,
    const float* __restrict__ x, const float* __restrict__ Wfc,
    const float* __restrict__ bfc,
    const float* __restrict__ gn, const float* __restrict__ bn,
    float* __restrict__ out){
  __shared__ u16 Ys[64*YSTR];
  __shared__ float cbs[ENC];
  __shared__ float wfs[3][ENC];
  __shared__ float mus[64], rss[64];
  const int t = threadIdx.x;
  const int mb = blockIdx.x * 64;
  for(int c=t; c<ENC; c+=256){
    cbs[c] = b2l[c] + bias2[c] + bfc[c];
    wfs[0][c] = Wfc[c]; wfs[1][c] = Wfc[ENC+c]; wfs[2][c] = Wfc[2*ENC+c];
  }
  const int w = t >> 6, lane = t & 63;
  const int l15 = lane & 15, g = lane >> 4;
  const int ar = mb + w*16 + l15;
  bf16x8 a[4];
  #pragma unroll
  for(int ks=0;ks<4;ks++)
    a[ks] = *(const bf16x8*)(aggb + (size_t)ar*128 + ks*32 + g*8);
  float xv0[4], xv1[4], xv2[4];
  #pragma unroll
  for(int r4=0;r4<4;r4++){
    const int rrow = mb + w*16 + g*4 + r4;
    xv0[r4] = x[rrow*3]; xv1[r4] = x[rrow*3+1]; xv2[r4] = x[rrow*3+2];
  }
  float rs[4] = {0,0,0,0}, rq[4] = {0,0,0,0};
  __syncthreads();
  #pragma unroll
  for(int sub=0; sub<6; ++sub){
    const int nb = sub*128;
    f32x4 acc[8];
    #pragma unroll
    for(int j=0;j<8;j++) acc[j]=(f32x4){0,0,0,0};
    #pragma unroll
    for(int j=0;j<8;j++){
      const int brn = nb + j*16 + l15;
      #pragma unroll
      for(int ks=0;ks<4;ks++){
        const bf16x8 b = *(const bf16x8*)(Wtb + (size_t)brn*128 + ks*32 + g*8);
        acc[j] = __builtin_amdgcn_mfma_f32_16x16x32_bf16(a[ks], b, acc[j], 0,0,0);
      }
    }
    #pragma unroll
    for(int j=0;j<8;j++){
      const int col = nb + j*16 + l15;
      const float cb = cbs[col];
      const float w0 = wfs[0][col], w1 = wfs[1][col], w2 = wfs[2][col];
      #pragma unroll
      for(int r4=0;r4<4;r4++){
        const int lrow = w*16 + g*4 + r4;
        const float y = acc[j][r4] + cb + xv0[r4]*w0 + xv1[r4]*w1 + xv2[r4]*w2;
        rs[r4] += y; rq[r4] += y*y;
        Ys[lrow*YSTR + col] = (u16)bf16rtne(y);
      }
    }
  }
  #pragma unroll
  for(int m=8;m>=1;m>>=1){
    #pragma unroll
    for(int r4=0;r4<4;r4++){
      rs[r4] += __shfl_xor(rs[r4], m, 64);
      rq[r4] += __shfl_xor(rq[r4], m, 64);
    }
  }
  if(l15 == 0){
    #pragma unroll
    for(int r4=0;r4<4;r4++){
      const int lrow = w*16 + g*4 + r4;
      const float mu = rs[r4] * (1.f/ENC);
      const float var = rq[r4] * (1.f/ENC) - mu*mu;
      mus[lrow] = mu;
      rss[lrow] = rsqrtf(var + EPSV);
    }
  }
  __syncthreads();
  float gv[12], bv[12];
  #pragma unroll
  for(int j2=0;j2<12;j2++){ gv[j2] = gn[lane + j2*64]; bv[j2] = bn[lane + j2*64]; }
  for(int r=0; r<16; ++r){
    const int lrow = w*16 + r;
    const float mu = mus[lrow], rstd = rss[lrow];
    float* orow = out + (size_t)(mb+lrow)*ENC;
    #pragma unroll
    for(int j2=0;j2<12;j2++){
      const float y = bf2f(Ys[lrow*YSTR + lane + j2*64]);
      orow[lane + j2*64] = (y - mu)*rstd*gv[j2] + bv[j2];
    }
  }
}

extern "C" void kernel_launch(void* const* d_in, const int* in_sizes, int n_in,
                              void* d_out, int out_size, void* d_ws, size_t ws_size,
                              hipStream_t stream) {
  const float* x    = (const float*)d_in[0];
  const int*   ei   = (const int*)  d_in[1];
  const float* Wfc  = (const float*)d_in[2];
  const float* bfc  = (const float*)d_in[3];
  const float* W1l  = (const float*)d_in[4];
  const float* b1l  = (const float*)d_in[5];
  const float* W1r  = (const float*)d_in[6];
  const float* b1r  = (const float*)d_in[7];
  const float* att1 = (const float*)d_in[8];
  const float* bias1= (const float*)d_in[9];
  const float* g1   = (const float*)d_in[10];
  const float* bb1  = (const float*)d_in[11];
  const float* W2l  = (const float*)d_in[12];
  const float* b2l  = (const float*)d_in[13];
  const float* W2r  = (const float*)d_in[14];
  const float* b2r  = (const float*)d_in[15];
  const float* att2 = (const float*)d_in[16];
  const float* bias2= (const float*)d_in[17];
  const float* gn   = (const float*)d_in[18];
  const float* bn   = (const float*)d_in[19];
  float* out = (float*)d_out;

  char* w = (char*)d_ws;
  auto alloc = [&](size_t bytes){ void* p = (void*)w; w += (bytes + 255) & ~(size_t)255; return p; };
  int*      hist     = (int*)     alloc((size_t)N_NODES*4);   // contiguous with cursor
  int*      cursor   = (int*)     alloc((size_t)N_NODES*4);
  int*      rowstart = (int*)     alloc((size_t)(N_NODES+1)*4);
  unsigned* sedge    = (unsigned*)alloc((size_t)EP*4);
  u16*      xl1b     = (u16*)     alloc((size_t)N_NODES*HID*2);
  u16*      xr1b     = (u16*)     alloc((size_t)N_NODES*HID*2);
  float4*   xpad     = (float4*)  alloc((size_t)N_NODES*16);
  float*    dotl1    = (float*)   alloc((size_t)N_NODES*4);
  float*    dotr1    = (float*)   alloc((size_t)N_NODES*4);
  float*    dotl2    = (float*)   alloc((size_t)N_NODES*4);
  float*    dotr2    = (float*)   alloc((size_t)N_NODES*4);
  float*    w1       = (float*)   alloc((size_t)EP*4);
  float*    w2       = (float*)   alloc((size_t)EP*4);
  float4*   agg4     = (float4*)  alloc((size_t)N_NODES*16);
  u16*      h1b      = (u16*)     alloc((size_t)N_NODES*HID*2);
  unsigned* h1p      = (unsigned*)alloc((size_t)N_NODES*64*4);
  u16*      aggb     = (u16*)     alloc((size_t)N_NODES*HID*2);
  u8*       xl8      = (u8*)      alloc((size_t)N_NODES*ENC);
  u16*      xr2u     = (u16*)     alloc((size_t)N_NODES*ENC*2);
  u16*      Wtb      = (u16*)     alloc((size_t)2*ENC*HID*2);
  float*    w2a      = (float*)   alloc((size_t)W2A_BLKS*4);

  hipMemsetAsync(hist, 0, (size_t)N_NODES*8, stream);   // hist + cursor

  prep_kernel<<<LIN1_BLKS+WPREP_BLKS+HIST_BLKS+W2A_BLKS, 256, 0, stream>>>(
      x, W1l, b1l, W1r, b1r, att1, W2l, W2r, b2l, b2r, att2, ei,
      xl1b, xr1b, xpad, dotl1, dotr1, Wtb, w2a, hist);
  scan_kernel<<<1, 1024, 0, stream>>>(hist, rowstart);
  scatter_kernel<<<EP/256, 256, 0, stream>>>(ei, rowstart, cursor, sedge);
  score1_kernel<<<EP/256, 256, 0, stream>>>(xl1b, xr1b, att1, dotl1, dotr1,
                                            sedge, w1);
  agg1_kernel<<<N_NODES/256, 256, 0, stream>>>(sedge, w1, xpad, rowstart, agg4);
  h1lin_kernel<<<N_NODES/4, 256, 0, stream>>>(agg4, W1l, b1l, bias1, g1, bb1,
                                              w2a, h1b, h1p, dotl2, dotr2);
  mfma_lin2_kernel<<<dim3(N_NODES/LBM, 2*ENC/LBN), 256, 0, stream>>>(
      h1b, Wtb, b2l, b2r, xl8, xr2u);
  score2_kernel<<<EP/256, 256, 0, stream>>>(xl8, xr2u, att2, dotl2, dotr2,
                                            sedge, w2);
  agg2_kernel<<<N_NODES/4, 256, 0, stream>>>(sedge, w2, h1p, rowstart, aggb);
  gemm3_mfma_kernel<<<N_NODES/64, 256, 0, stream>>>(aggb, Wtb, b2l, bias2,
                                                    x, Wfc, bfc, gn, bn, out);
}

// Round 10
// 190.172 us; speedup vs baseline: 1.3048x; 1.3048x over previous
//
#include <hip/hip_runtime.h>

#define N_NODES 16384
#define N_EDGES 262144
#define EP (N_EDGES + N_NODES)   // with self-loops
#define HID 128
#define ENC 768
#define ENCP (ENC/2)
#define EPSV 1e-5f

typedef unsigned short u16;
typedef unsigned char u8;
using f32x4  = __attribute__((ext_vector_type(4))) float;
using bf16x8 = __attribute__((ext_vector_type(8))) short;
using v2f    = __attribute__((ext_vector_type(2))) float;

__device__ __forceinline__ float wave_sum(float v){
  #pragma unroll
  for(int m=32;m>=1;m>>=1) v += __shfl_xor(v, m, 64);
  return v;
}
__device__ __forceinline__ unsigned bf16rtne(float f){
  const unsigned u = __float_as_uint(f);
  return (u + 0x7fffu + ((u>>16)&1u)) >> 16;
}
__device__ __forceinline__ unsigned pack2(float a, float b){
  return bf16rtne(a) | (bf16rtne(b) << 16);
}
__device__ __forceinline__ float bf2f(u16 h){ return __uint_as_float(((unsigned)h) << 16); }
__device__ __forceinline__ float plo(unsigned u){ return __uint_as_float(u << 16); }
__device__ __forceinline__ float phi(unsigned u){ return __uint_as_float(u & 0xffff0000u); }
__device__ __forceinline__ u8 f2fp8(float v){
  return (u8)(__builtin_amdgcn_cvt_pk_fp8_f32(v, v, 0, false) & 0xff);
}

// 4 fp8 channels (one dword) against sg/xr registers j..j+3
#define Q4(ax, j, q) { \
  const v2f f01 = __builtin_amdgcn_cvt_pk_f32_fp8(ax, false); \
  const v2f f23 = __builtin_amdgcn_cvt_pk_f32_fp8(ax, true);  \
  q = fmaf(sg[j],   __builtin_fabsf(f01.x+xr[j]),   q); \
  q = fmaf(sg[j+1], __builtin_fabsf(f01.y+xr[j+1]), q); \
  q = fmaf(sg[j+2], __builtin_fabsf(f23.x+xr[j+2]), q); \
  q = fmaf(sg[j+3], __builtin_fabsf(f23.y+xr[j+3]), q); }

// ---- merged prep: lin1 (+att1 dots), Wtb transpose, dst histogram, W2@att2 ----
#define LIN1_BLKS (N_NODES/4)            // 4096 (one wave per node)
#define WPREP_BLKS (2*ENC*HID/256)       // 768
#define HIST_BLKS (EP/256)               // 1088
#define W2A_BLKS 258                     // 128 l + 128 r + cl + cr
__global__ __launch_bounds__(256) void prep_kernel(
    const float* __restrict__ x,
    const float* __restrict__ W1l, const float* __restrict__ b1l,
    const float* __restrict__ W1r, const float* __restrict__ b1r,
    const float* __restrict__ att1,
    const float* __restrict__ W2l, const float* __restrict__ W2r,
    const float* __restrict__ b2l, const float* __restrict__ b2r,
    const float* __restrict__ att2,
    const int* __restrict__ ei,
    unsigned* __restrict__ xl1p, unsigned* __restrict__ xr1p,
    float* __restrict__ dotl1, float* __restrict__ dotr1,
    u16* __restrict__ Wtb, float* __restrict__ w2a,
    int* __restrict__ hist){
  const int bid = blockIdx.x;
  if(bid < LIN1_BLKS){
    const int lane = threadIdx.x & 63;
    const int n = bid*4 + (threadIdx.x >> 6);
    const float x0 = x[n*3], x1 = x[n*3+1], x2 = x[n*3+2];
    const int c0 = lane, c1 = lane + 64;
    const float la = x0*W1l[c0] + x1*W1l[HID+c0] + x2*W1l[2*HID+c0] + b1l[c0];
    const float lb = x0*W1l[c1] + x1*W1l[HID+c1] + x2*W1l[2*HID+c1] + b1l[c1];
    const float ra = x0*W1r[c0] + x1*W1r[HID+c0] + x2*W1r[2*HID+c0] + b1r[c0];
    const float rb = x0*W1r[c1] + x1*W1r[HID+c1] + x2*W1r[2*HID+c1] + b1r[c1];
    const float aa = att1[c0], ab = att1[c1];
    const float dl = wave_sum(la*aa + lb*ab);
    const float dr = wave_sum(ra*aa + rb*ab);
    if(lane == 0){ dotl1[n] = 0.6f*dl; dotr1[n] = 0.6f*dr; }
    xl1p[n*64+lane] = pack2(la, lb);
    xr1p[n*64+lane] = pack2(ra, rb);
  } else if(bid < LIN1_BLKS + WPREP_BLKS){
    const int idx = (bid - LIN1_BLKS)*256 + threadIdx.x;
    const int n = idx >> 7, k = idx & 127;
    const float v = (n < ENC) ? W2l[k*ENC + n] : W2r[k*ENC + (n-ENC)];
    Wtb[idx] = (u16)bf16rtne(v);
  } else if(bid < LIN1_BLKS + WPREP_BLKS + HIST_BLKS){
    const int i = (bid - LIN1_BLKS - WPREP_BLKS)*256 + threadIdx.x;
    const int dst = (i < N_EDGES) ? ei[N_EDGES + i] : (i - N_EDGES);
    atomicAdd(&hist[dst], 1);
  } else {
    // w2a[idx]: idx<128 -> W2l@att2 row k; idx<256 -> W2r@att2; 256/257 -> att2.b2l / att2.b2r
    const int idx = bid - (LIN1_BLKS + WPREP_BLKS + HIST_BLKS);
    const float* src = (idx < 128) ? (W2l + (size_t)idx*ENC)
                     : (idx < 256) ? (W2r + (size_t)(idx-128)*ENC)
                     : (idx == 256) ? b2l : b2r;
    float partial = 0.f;
    for(int c = threadIdx.x; c < ENC; c += 256) partial += src[c]*att2[c];
    partial = wave_sum(partial);
    __shared__ float red4[4];
    if((threadIdx.x & 63) == 0) red4[threadIdx.x >> 6] = partial;
    __syncthreads();
    if(threadIdx.x == 0) w2a[idx] = red4[0]+red4[1]+red4[2]+red4[3];
  }
}

// ---- single-block exclusive scan over N=16384 (1024 thr x 16 items) ----
__global__ __launch_bounds__(1024) void scan_kernel(
    const int* __restrict__ hist, int* __restrict__ rowstart){
  __shared__ int sums[1024];
  const int t = threadIdx.x;
  const int base = t*16;
  int loc[16];
  int s = 0;
  #pragma unroll
  for(int i=0;i<16;i++){ loc[i] = s; s += hist[base+i]; }
  sums[t] = s;
  __syncthreads();
  for(int off=1; off<1024; off<<=1){
    int v = 0;
    if(t >= off) v = sums[t-off];
    __syncthreads();
    if(t >= off) sums[t] += v;
    __syncthreads();
  }
  const int prev = (t==0) ? 0 : sums[t-1];
  #pragma unroll
  for(int i=0;i<16;i++) rowstart[base+i] = prev + loc[i];
  if(t == 1023) rowstart[N_NODES] = EP;
}

// ---- CSR build: scatter src ids into dst-sorted order ----
__global__ __launch_bounds__(256) void scatter_kernel(
    const int* __restrict__ ei, const int* __restrict__ rowstart,
    int* __restrict__ cursor, int* __restrict__ ssrc){
  const int i = blockIdx.x*256 + threadIdx.x;        // exactly EP threads
  const int src = (i < N_EDGES) ? ei[i]           : (i - N_EDGES);
  const int dst = (i < N_EDGES) ? ei[N_EDGES + i] : (i - N_EDGES);
  const int pos = rowstart[dst] + atomicAdd(&cursor[dst], 1);
  ssrc[pos] = src;
}

// ---- GAT layer 1 (abs-decomposed scores, 4-edge unroll) ----
__global__ __launch_bounds__(256) void node1_kernel(
    const unsigned* __restrict__ xl1p, const unsigned* __restrict__ xr1p,
    const float* __restrict__ att1,
    const float* __restrict__ dotl1, const float* __restrict__ dotr1,
    const float* __restrict__ bias1,
    const float* __restrict__ g1, const float* __restrict__ b1,
    const float* __restrict__ w2a,
    const int* __restrict__ rowstart, const int* __restrict__ ssrc,
    u16* __restrict__ h1b, unsigned* __restrict__ h1p,
    float* __restrict__ dotl2, float* __restrict__ dotr2){
  const int lane = threadIdx.x & 63;
  const int n = blockIdx.x*4 + (threadIdx.x >> 6);
  const unsigned xru = xr1p[n*64 + lane];
  const float xra = plo(xru), xrb = phi(xru);
  const float sa = 0.4f*att1[lane], sb = 0.4f*att1[lane+64];
  const float ebase = dotr1[n];
  float acc0 = 0.f, acc1 = 0.f, denom = 0.f;
  int p = rowstart[n];
  const int p1 = rowstart[n+1];
  for(; p+3 < p1; p += 4){
    const int s0 = ssrc[p],   s1 = ssrc[p+1];
    const int s2 = ssrc[p+2], s3 = ssrc[p+3];
    const unsigned u0 = xl1p[s0*64 + lane];
    const unsigned u1 = xl1p[s1*64 + lane];
    const unsigned u2 = xl1p[s2*64 + lane];
    const unsigned u3 = xl1p[s3*64 + lane];
    const float dl0 = dotl1[s0], dl1 = dotl1[s1];
    const float dl2 = dotl1[s2], dl3 = dotl1[s3];
    const float a0 = plo(u0), b0 = phi(u0);
    const float a1 = plo(u1), b1v = phi(u1);
    const float a2 = plo(u2), b2v = phi(u2);
    const float a3 = plo(u3), b3v = phi(u3);
    float q0 = fmaf(sa, __builtin_fabsf(a0+xra), sb*__builtin_fabsf(b0+xrb));
    float q1 = fmaf(sa, __builtin_fabsf(a1+xra), sb*__builtin_fabsf(b1v+xrb));
    float q2 = fmaf(sa, __builtin_fabsf(a2+xra), sb*__builtin_fabsf(b2v+xrb));
    float q3 = fmaf(sa, __builtin_fabsf(a3+xra), sb*__builtin_fabsf(b3v+xrb));
    #pragma unroll
    for(int m=32;m>=1;m>>=1){
      q0 += __shfl_xor(q0, m, 64);
      q1 += __shfl_xor(q1, m, 64);
      q2 += __shfl_xor(q2, m, 64);
      q3 += __shfl_xor(q3, m, 64);
    }
    const float w0 = __expf(q0 + dl0 + ebase), w1 = __expf(q1 + dl1 + ebase);
    const float w2 = __expf(q2 + dl2 + ebase), w3 = __expf(q3 + dl3 + ebase);
    denom += (w0+w1) + (w2+w3);
    acc0 += w0*a0 + w1*a1 + w2*a2 + w3*a3;
    acc1 += w0*b0 + w1*b1v + w2*b2v + w3*b3v;
  }
  for(; p < p1; ++p){
    const int s0 = ssrc[p];
    const unsigned u0 = xl1p[s0*64 + lane];
    const float a0 = plo(u0), b0 = phi(u0);
    const float q = wave_sum(fmaf(sa, __builtin_fabsf(a0+xra), sb*__builtin_fabsf(b0+xrb)));
    const float w0 = __expf(q + dotl1[s0] + ebase);
    denom += w0; acc0 += w0*a0; acc1 += w0*b0;
  }
  const float inv = 1.f/denom;
  const float y0 = acc0*inv + bias1[lane];
  const float y1 = acc1*inv + bias1[lane+64];
  const float mu  = wave_sum(y0+y1) * (1.f/HID);
  const float d0 = y0-mu, d1 = y1-mu;
  const float var = wave_sum(d0*d0 + d1*d1) * (1.f/HID);
  const float r = rsqrtf(var + EPSV);
  float z0 = d0*r*g1[lane] + b1[lane];
  float z1 = d1*r*g1[lane+64] + b1[lane+64];
  z0 = z0 > 0.f ? z0 : expm1f(z0);        // ELU(alpha=1)
  z1 = z1 > 0.f ? z1 : expm1f(z1);
  h1b[n*HID+lane]    = (u16)bf16rtne(z0);
  h1b[n*HID+lane+64] = (u16)bf16rtne(z1);
  h1p[n*64+lane]     = pack2(z0, z1);
  // layer-2 per-node linear score terms: 0.6*(att2 . xl2/xr2[n])
  float dl2 = z0*w2a[lane]     + z1*w2a[lane+64];
  float dr2 = z0*w2a[128+lane] + z1*w2a[128+lane+64];
  #pragma unroll
  for(int m=32;m>=1;m>>=1){
    dl2 += __shfl_xor(dl2, m, 64);
    dr2 += __shfl_xor(dr2, m, 64);
  }
  if(lane == 0){
    dotl2[n] = 0.6f*(dl2 + w2a[256]);
    dotr2[n] = 0.6f*(dr2 + w2a[257]);
  }
}

// ---- MFMA GEMM: l-half -> fp8 xl8 (random src gather), r-half -> bf16 xr2u ----
#define LBM 128
#define LBN 128
__global__ __launch_bounds__(256) void mfma_lin2_kernel(
    const u16* __restrict__ h1b, const u16* __restrict__ Wtb,
    const float* __restrict__ b2l, const float* __restrict__ b2r,
    u8* __restrict__ xl8, u16* __restrict__ xr2u){
  __shared__ __align__(16) u16 Cs[LBM*128];   // 32 KB bounce, swizzled rows
  const int t = threadIdx.x;
  const int mb = blockIdx.x * LBM;
  const int nb = blockIdx.y * LBN;
  const int w = t >> 6, lane = t & 63;
  const int l15 = lane & 15, g = lane >> 4;
  const int ar0 = mb + w*32 + l15, ar1 = ar0 + 16;
  bf16x8 a0[4], a1[4];
  #pragma unroll
  for(int ks=0;ks<4;ks++){
    a0[ks] = *(const bf16x8*)(h1b + (size_t)ar0*128 + ks*32 + g*8);
    a1[ks] = *(const bf16x8*)(h1b + (size_t)ar1*128 + ks*32 + g*8);
  }
  f32x4 acc0[8], acc1[8];
  #pragma unroll
  for(int j=0;j<8;j++){ acc0[j]=(f32x4){0,0,0,0}; acc1[j]=(f32x4){0,0,0,0}; }
  #pragma unroll
  for(int j=0;j<8;j++){
    const int brn = nb + j*16 + l15;
    #pragma unroll
    for(int ks=0;ks<4;ks++){
      const bf16x8 b = *(const bf16x8*)(Wtb + (size_t)brn*128 + ks*32 + g*8);
      acc0[j] = __builtin_amdgcn_mfma_f32_16x16x32_bf16(a0[ks], b, acc0[j], 0,0,0);
      acc1[j] = __builtin_amdgcn_mfma_f32_16x16x32_bf16(a1[ks], b, acc1[j], 0,0,0);
    }
  }
  if(nb < ENC){
    // fp8 epilogue (src score table)
    u8* Cs8 = (u8*)Cs;
    float biasj[8];
    #pragma unroll
    for(int j=0;j<8;j++) biasj[j] = b2l[nb + j*16 + l15];
    #pragma unroll
    for(int j=0;j<8;j++){
      const int col = j*16 + l15;
      #pragma unroll
      for(int r4=0;r4<4;r4++){
        const int row0 = w*32 + g*4 + r4;         // C/D: col=lane&15, row=(lane>>4)*4+reg
        Cs8[row0*128 + (col ^ ((row0&7)<<4))] = f2fp8(acc0[j][r4] + biasj[j]);
        const int row1 = row0 + 16;
        Cs8[row1*128 + (col ^ ((row1&7)<<4))] = f2fp8(acc1[j][r4] + biasj[j]);
      }
    }
    __syncthreads();
    #pragma unroll
    for(int idx=t; idx<LBM*8; idx+=256){
      const int row = idx >> 3, ch = idx & 7;
      const uint4 v = *(const uint4*)(Cs8 + row*128 + ((ch*16) ^ ((row&7)<<4)));
      *(uint4*)(xl8 + (size_t)(mb+row)*ENC + nb + ch*16) = v;
    }
  } else {
    // bf16 epilogue (dst score table — loop-invariant per node in node2b)
    const float* bsrc = b2r + (nb - ENC);
    float biasj[8];
    #pragma unroll
    for(int j=0;j<8;j++) biasj[j] = bsrc[j*16 + l15];
    #pragma unroll
    for(int j=0;j<8;j++){
      const int coll = j*16 + l15;
      #pragma unroll
      for(int r4=0;r4<4;r4++){
        const int row0 = w*32 + g*4 + r4;
        *(u16*)((char*)Cs + row0*256 + ((coll*2) ^ ((row0&7)<<4))) =
            (u16)bf16rtne(acc0[j][r4] + biasj[j]);
        const int row1 = row0 + 16;
        *(u16*)((char*)Cs + row1*256 + ((coll*2) ^ ((row1&7)<<4))) =
            (u16)bf16rtne(acc1[j][r4] + biasj[j]);
      }
    }
    __syncthreads();
    u16* dst0 = xr2u + (nb - ENC);
    const int rr = t >> 4, cc = t & 15;
    #pragma unroll
    for(int it=0; it<8; ++it){
      const int row = it*16 + rr;
      const uint4 v = *(const uint4*)((const char*)Cs + row*256 + ((cc*16) ^ ((row&7)<<4)));
      *(uint4*)(dst0 + (size_t)(mb+row)*ENC + cc*8) = v;
    }
  }
}

// ---- GAT layer 2: per-lane-contiguous channels (12/lane), fp8 src row as one
//      dwordx3; sg/xr loop-invariant in regs; 4-edge unroll; aggregate bf16 h1p ----
__global__ __launch_bounds__(256) void node2b_kernel(
    const u8* __restrict__ xl8, const u8* __restrict__ xr2u8,
    const float* __restrict__ att2,
    const float* __restrict__ dotl2, const float* __restrict__ dotr2,
    const unsigned* __restrict__ h1p,
    const int* __restrict__ rowstart, const int* __restrict__ ssrc,
    u16* __restrict__ aggb){
  const int lane = threadIdx.x & 63;
  const int n = blockIdx.x*4 + (threadIdx.x >> 6);
  // loop-invariant: this lane's 12 channels of 0.4*att2 and xr2[n]
  float sg[12], xr[12];
  {
    const float4* A4 = (const float4*)(att2 + lane*12);   // 48B stride, 16-aligned
    const float4 s0 = A4[0], s1 = A4[1], s2 = A4[2];
    sg[0]=0.4f*s0.x; sg[1]=0.4f*s0.y; sg[2]=0.4f*s0.z; sg[3]=0.4f*s0.w;
    sg[4]=0.4f*s1.x; sg[5]=0.4f*s1.y; sg[6]=0.4f*s1.z; sg[7]=0.4f*s1.w;
    sg[8]=0.4f*s2.x; sg[9]=0.4f*s2.y; sg[10]=0.4f*s2.z; sg[11]=0.4f*s2.w;
    const u8* xrrow = xr2u8 + (size_t)n*(ENC*2) + lane*24;
    const uint2 r0 = *(const uint2*)(xrrow);
    const uint2 r1 = *(const uint2*)(xrrow + 8);
    const uint2 r2 = *(const uint2*)(xrrow + 16);
    xr[0]=plo(r0.x); xr[1]=phi(r0.x); xr[2]=plo(r0.y); xr[3]=phi(r0.y);
    xr[4]=plo(r1.x); xr[5]=phi(r1.x); xr[6]=plo(r1.y); xr[7]=phi(r1.y);
    xr[8]=plo(r2.x); xr[9]=phi(r2.x); xr[10]=plo(r2.y); xr[11]=phi(r2.y);
  }
  const float ebase = dotr2[n];
  float denom = 0.f, acc0 = 0.f, acc1 = 0.f;
  int p = rowstart[n];
  const int p1 = rowstart[n+1];
  for(; p+3 < p1; p += 4){
    const int s0 = ssrc[p],   s1 = ssrc[p+1];
    const int s2 = ssrc[p+2], s3 = ssrc[p+3];
    const uint3 a0 = *(const uint3*)(xl8 + (size_t)s0*ENC + lane*12);
    const uint3 a1 = *(const uint3*)(xl8 + (size_t)s1*ENC + lane*12);
    const uint3 a2 = *(const uint3*)(xl8 + (size_t)s2*ENC + lane*12);
    const uint3 a3 = *(const uint3*)(xl8 + (size_t)s3*ENC + lane*12);
    const float dl0 = dotl2[s0], dl1 = dotl2[s1];
    const float dl2 = dotl2[s2], dl3 = dotl2[s3];
    const unsigned h0 = h1p[s0*64 + lane];
    const unsigned h1 = h1p[s1*64 + lane];
    const unsigned h2 = h1p[s2*64 + lane];
    const unsigned h3 = h1p[s3*64 + lane];
    float q0 = 0.f, q1 = 0.f, q2 = 0.f, q3 = 0.f;
    Q4(a0.x, 0, q0) Q4(a0.y, 4, q0) Q4(a0.z, 8, q0)
    Q4(a1.x, 0, q1) Q4(a1.y, 4, q1) Q4(a1.z, 8, q1)
    Q4(a2.x, 0, q2) Q4(a2.y, 4, q2) Q4(a2.z, 8, q2)
    Q4(a3.x, 0, q3) Q4(a3.y, 4, q3) Q4(a3.z, 8, q3)
    #pragma unroll
    for(int m=32;m>=1;m>>=1){
      q0 += __shfl_xor(q0, m, 64);
      q1 += __shfl_xor(q1, m, 64);
      q2 += __shfl_xor(q2, m, 64);
      q3 += __shfl_xor(q3, m, 64);
    }
    const float w0 = __expf(q0 + dl0 + ebase), w1 = __expf(q1 + dl1 + ebase);
    const float w2 = __expf(q2 + dl2 + ebase), w3 = __expf(q3 + dl3 + ebase);
    denom += (w0+w1) + (w2+w3);
    acc0 += w0*plo(h0) + w1*plo(h1) + w2*plo(h2) + w3*plo(h3);
    acc1 += w0*phi(h0) + w1*phi(h1) + w2*phi(h2) + w3*phi(h3);
  }
  for(; p < p1; ++p){
    const int s0 = ssrc[p];
    const uint3 a0 = *(const uint3*)(xl8 + (size_t)s0*ENC + lane*12);
    float q0 = 0.f;
    Q4(a0.x, 0, q0) Q4(a0.y, 4, q0) Q4(a0.z, 8, q0)
    const unsigned h0 = h1p[s0*64 + lane];
    const float w0 = __expf(wave_sum(q0) + dotl2[s0] + ebase);
    denom += w0; acc0 += w0*plo(h0); acc1 += w0*phi(h0);
  }
  const float inv = 1.f/denom;
  aggb[n*HID+lane]    = (u16)bf16rtne(acc0*inv);
  aggb[n*HID+lane+64] = (u16)bf16rtne(acc1*inv);
}

// ---- final fused: out = LN( aggb@W2l + b2l + bias2 + x@Wfc + bfc ) ----
#define YSTR 770
__global__ __launch_bounds__(256) void gemm3_mfma_kernel(
    const u16* __restrict__ aggb, const u16* __restrict__ Wtb,
    const float* __restrict__ b2l, const float* __restrict__ bias2,
    const float* __restrict__ x, const float* __restrict__ Wfc,
    const float* __restrict__ bfc,
    const float* __restrict__ gn, const float* __restrict__ bn,
    float* __restrict__ out){
  __shared__ u16 Ys[64*YSTR];
  __shared__ float cbs[ENC];
  __shared__ float wfs[3][ENC];
  __shared__ float mus[64], rss[64];
  const int t = threadIdx.x;
  const int mb = blockIdx.x * 64;
  for(int c=t; c<ENC; c+=256){
    cbs[c] = b2l[c] + bias2[c] + bfc[c];
    wfs[0][c] = Wfc[c]; wfs[1][c] = Wfc[ENC+c]; wfs[2][c] = Wfc[2*ENC+c];
  }
  const int w = t >> 6, lane = t & 63;
  const int l15 = lane & 15, g = lane >> 4;
  const int ar = mb + w*16 + l15;
  bf16x8 a[4];
  #pragma unroll
  for(int ks=0;ks<4;ks++)
    a[ks] = *(const bf16x8*)(aggb + (size_t)ar*128 + ks*32 + g*8);
  float xv0[4], xv1[4], xv2[4];
  #pragma unroll
  for(int r4=0;r4<4;r4++){
    const int rrow = mb + w*16 + g*4 + r4;
    xv0[r4] = x[rrow*3]; xv1[r4] = x[rrow*3+1]; xv2[r4] = x[rrow*3+2];
  }
  float rs[4] = {0,0,0,0}, rq[4] = {0,0,0,0};
  __syncthreads();
  #pragma unroll
  for(int sub=0; sub<6; ++sub){
    const int nb = sub*128;
    f32x4 acc[8];
    #pragma unroll
    for(int j=0;j<8;j++) acc[j]=(f32x4){0,0,0,0};
    #pragma unroll
    for(int j=0;j<8;j++){
      const int brn = nb + j*16 + l15;
      #pragma unroll
      for(int ks=0;ks<4;ks++){
        const bf16x8 b = *(const bf16x8*)(Wtb + (size_t)brn*128 + ks*32 + g*8);
        acc[j] = __builtin_amdgcn_mfma_f32_16x16x32_bf16(a[ks], b, acc[j], 0,0,0);
      }
    }
    #pragma unroll
    for(int j=0;j<8;j++){
      const int col = nb + j*16 + l15;
      const float cb = cbs[col];
      const float w0 = wfs[0][col], w1 = wfs[1][col], w2 = wfs[2][col];
      #pragma unroll
      for(int r4=0;r4<4;r4++){
        const int lrow = w*16 + g*4 + r4;
        const float y = acc[j][r4] + cb + xv0[r4]*w0 + xv1[r4]*w1 + xv2[r4]*w2;
        rs[r4] += y; rq[r4] += y*y;
        Ys[lrow*YSTR + col] = (u16)bf16rtne(y);
      }
    }
  }
  #pragma unroll
  for(int m=8;m>=1;m>>=1){
    #pragma unroll
    for(int r4=0;r4<4;r4++){
      rs[r4] += __shfl_xor(rs[r4], m, 64);
      rq[r4] += __shfl_xor(rq[r4], m, 64);
    }
  }
  if(l15 == 0){
    #pragma unroll
    for(int r4=0;r4<4;r4++){
      const int lrow = w*16 + g*4 + r4;
      const float mu = rs[r4] * (1.f/ENC);
      const float var = rq[r4] * (1.f/ENC) - mu*mu;
      mus[lrow] = mu;
      rss[lrow] = rsqrtf(var + EPSV);
    }
  }
  __syncthreads();
  float gv[12], bv[12];
  #pragma unroll
  for(int j2=0;j2<12;j2++){ gv[j2] = gn[lane + j2*64]; bv[j2] = bn[lane + j2*64]; }
  for(int r=0; r<16; ++r){
    const int lrow = w*16 + r;
    const float mu = mus[lrow], rstd = rss[lrow];
    float* orow = out + (size_t)(mb+lrow)*ENC;
    #pragma unroll
    for(int j2=0;j2<12;j2++){
      const float y = bf2f(Ys[lrow*YSTR + lane + j2*64]);
      orow[lane + j2*64] = (y - mu)*rstd*gv[j2] + bv[j2];
    }
  }
}

extern "C" void kernel_launch(void* const* d_in, const int* in_sizes, int n_in,
                              void* d_out, int out_size, void* d_ws, size_t ws_size,
                              hipStream_t stream) {
  const float* x    = (const float*)d_in[0];
  const int*   ei   = (const int*)  d_in[1];
  const float* Wfc  = (const float*)d_in[2];
  const float* bfc  = (const float*)d_in[3];
  const float* W1l  = (const float*)d_in[4];
  const float* b1l  = (const float*)d_in[5];
  const float* W1r  = (const float*)d_in[6];
  const float* b1r  = (const float*)d_in[7];
  const float* att1 = (const float*)d_in[8];
  const float* bias1= (const float*)d_in[9];
  const float* g1   = (const float*)d_in[10];
  const float* bb1  = (const float*)d_in[11];
  const float* W2l  = (const float*)d_in[12];
  const float* b2l  = (const float*)d_in[13];
  const float* W2r  = (const float*)d_in[14];
  const float* b2r  = (const float*)d_in[15];
  const float* att2 = (const float*)d_in[16];
  const float* bias2= (const float*)d_in[17];
  const float* gn   = (const float*)d_in[18];
  const float* bn   = (const float*)d_in[19];
  float* out = (float*)d_out;

  char* w = (char*)d_ws;
  auto alloc = [&](size_t bytes){ void* p = (void*)w; w += (bytes + 255) & ~(size_t)255; return p; };
  int*      hist     = (int*)     alloc((size_t)N_NODES*4);   // contiguous with cursor
  int*      cursor   = (int*)     alloc((size_t)N_NODES*4);
  int*      rowstart = (int*)     alloc((size_t)(N_NODES+1)*4);
  int*      ssrc     = (int*)     alloc((size_t)EP*4);
  unsigned* xl1p     = (unsigned*)alloc((size_t)N_NODES*64*4);
  unsigned* xr1p     = (unsigned*)alloc((size_t)N_NODES*64*4);
  float*    dotl1    = (float*)   alloc((size_t)N_NODES*4);
  float*    dotr1    = (float*)   alloc((size_t)N_NODES*4);
  float*    dotl2    = (float*)   alloc((size_t)N_NODES*4);
  float*    dotr2    = (float*)   alloc((size_t)N_NODES*4);
  u16*      h1b      = (u16*)     alloc((size_t)N_NODES*HID*2);
  unsigned* h1p      = (unsigned*)alloc((size_t)N_NODES*64*4);
  u16*      aggb     = (u16*)     alloc((size_t)N_NODES*HID*2);
  u8*       xl8      = (u8*)      alloc((size_t)N_NODES*ENC);
  u16*      xr2u     = (u16*)     alloc((size_t)N_NODES*ENC*2);
  u16*      Wtb      = (u16*)     alloc((size_t)2*ENC*HID*2);
  float*    w2a      = (float*)   alloc((size_t)W2A_BLKS*4);

  hipMemsetAsync(hist, 0, (size_t)N_NODES*8, stream);   // hist + cursor

  prep_kernel<<<LIN1_BLKS+WPREP_BLKS+HIST_BLKS+W2A_BLKS, 256, 0, stream>>>(
      x, W1l, b1l, W1r, b1r, att1, W2l, W2r, b2l, b2r, att2, ei,
      xl1p, xr1p, dotl1, dotr1, Wtb, w2a, hist);
  scan_kernel<<<1, 1024, 0, stream>>>(hist, rowstart);
  scatter_kernel<<<EP/256, 256, 0, stream>>>(ei, rowstart, cursor, ssrc);
  node1_kernel<<<N_NODES/4, 256, 0, stream>>>(xl1p, xr1p, att1, dotl1, dotr1,
                                              bias1, g1, bb1, w2a,
                                              rowstart, ssrc, h1b, h1p, dotl2, dotr2);
  mfma_lin2_kernel<<<dim3(N_NODES/LBM, 2*ENC/LBN), 256, 0, stream>>>(
      h1b, Wtb, b2l, b2r, xl8, xr2u);
  node2b_kernel<<<N_NODES/4, 256, 0, stream>>>(xl8, (const u8*)xr2u, att2,
                                               dotl2, dotr2, h1p,
                                               rowstart, ssrc, aggb);
  gemm3_mfma_kernel<<<N_NODES/64, 256, 0, stream>>>(aggb, Wtb, b2l, bias2,
                                                    x, Wfc, bfc, gn, bn, out);
}